// Round 3
// baseline (276.445 us; speedup 1.0000x reference)
//
#include <hip/hip_runtime.h>

// Problem constants (fixed by reference setup_inputs)
constexpr int B_ = 8;
constexpr int N_ = 16;
constexpr int H_ = 368;
constexpr int W_ = 640;
constexpr int P_ = H_ * W_;          // 235520 pixels per image
constexpr int C_ = 12;               // instance ids 1..12
constexpr float MARGIN_VAR_ = 0.5f;
constexpr float MARGIN_DIST_ = 3.0f;

// Workspace layout (floats)
constexpr int OFF_SUMS = 0;                      // [B][C][N] feature sums
constexpr int OFF_CNT  = OFF_SUMS + B_*C_*N_;    // [B][C]    pixel counts
constexpr int OFF_CEN  = OFF_CNT  + B_*C_;       // [B][C][N] centers
constexpr int OFF_W    = OFF_CEN  + B_*C_*N_;    // [B][C]    pull weights
constexpr int WS_FLOATS = OFF_W + B_*C_;

constexpr int TPB    = 256;            // 4 waves
constexpr int CHUNK  = 1024;           // pixels per block (k_accum & k_pull)
constexpr int BPI    = P_ / CHUNK;     // 230 chunks per image (exact)
constexpr int CG     = 4;              // channel groups (4 channels per block)

__device__ __forceinline__ float wave_reduce(float a) {
    #pragma unroll
    for (int off = 32; off > 0; off >>= 1) a += __shfl_down(a, off, 64);
    return a;
}

// ---------------------------------------------------------------------------
// Kernel 1: per-class feature sums + counts.
// Block = 1024 pixels x 4 channels (one channel per wave). Register
// compare-select accumulation (no LDS atomics), labels staged once in LDS.
// Counts computed only by cg==0 blocks.
// ---------------------------------------------------------------------------
__global__ __launch_bounds__(TPB) void k_accum(const float* __restrict__ feat,
                                               const int* __restrict__ gt,
                                               float* __restrict__ ws) {
    __shared__ int4  s_lab4[CHUNK / 4];    // 256 int4 = 1024 labels
    __shared__ float s_red[TPB / 64][C_];

    const int tid  = threadIdx.x;
    const int lane = tid & 63, wid = tid >> 6;
    const int bid  = blockIdx.x;
    const int b     = bid / (BPI * CG);
    const int rem   = bid % (BPI * CG);
    const int chunk = rem / CG;
    const int cg    = rem % CG;
    const int base  = chunk * CHUNK;

    const int*   __restrict__ gb = gt   + (size_t)b * P_ + base;
    const float* __restrict__ fb = feat + (size_t)b * N_ * P_ + base;

    // stage labels (one int4 per thread covers the whole chunk)
    const int4 lb0 = *(const int4*)(gb + tid * 4);
    s_lab4[tid] = lb0;

    // counts: only channel-group-0 blocks
    if (cg == 0) {
        float cnt[C_];
        #pragma unroll
        for (int c = 0; c < C_; ++c) cnt[c] = 0.f;
        #pragma unroll
        for (int c = 0; c < C_; ++c) {
            cnt[c] += (lb0.x == c + 1) ? 1.f : 0.f;
            cnt[c] += (lb0.y == c + 1) ? 1.f : 0.f;
            cnt[c] += (lb0.z == c + 1) ? 1.f : 0.f;
            cnt[c] += (lb0.w == c + 1) ? 1.f : 0.f;
        }
        #pragma unroll
        for (int c = 0; c < C_; ++c) {
            const float r = wave_reduce(cnt[c]);
            if (lane == 0) s_red[wid][c] = r;
        }
    }
    __syncthreads();
    if (cg == 0 && tid < C_) {
        float t = 0.f;
        #pragma unroll
        for (int w = 0; w < TPB / 64; ++w) t += s_red[w][tid];
        atomicAdd(&ws[OFF_CNT + b * C_ + tid], t);
    }

    // per-wave channel accumulation
    const int n = cg * (TPB / 64) + wid;           // channel owned by this wave
    const float* __restrict__ fp = fb + (size_t)n * P_;

    float acc[C_];
    #pragma unroll
    for (int c = 0; c < C_; ++c) acc[c] = 0.f;

    #pragma unroll
    for (int i = 0; i < CHUNK / 256; ++i) {        // 4 iters, fully unrolled
        const int idx = i * 64 + lane;             // float4 index in chunk
        const float4 v  = *(const float4*)(fp + idx * 4);
        const int4   lb = s_lab4[idx];
        #pragma unroll
        for (int c = 0; c < C_; ++c) {
            acc[c] += (lb.x == c + 1) ? v.x : 0.f;
            acc[c] += (lb.y == c + 1) ? v.y : 0.f;
            acc[c] += (lb.z == c + 1) ? v.z : 0.f;
            acc[c] += (lb.w == c + 1) ? v.w : 0.f;
        }
    }
    #pragma unroll
    for (int c = 0; c < C_; ++c) {
        const float r = wave_reduce(acc[c]);
        if (lane == 0)
            atomicAdd(&ws[OFF_SUMS + ((size_t)b * C_ + c) * N_ + n], r);
    }
}

// ---------------------------------------------------------------------------
// Kernel 2 (1 block): centers, n_inst, pull weights, push loss -> out[0]
// ---------------------------------------------------------------------------
__global__ __launch_bounds__(TPB) void k_centers_push(float* __restrict__ ws,
                                                      float* __restrict__ out) {
    __shared__ float red[TPB];
    __shared__ float s_ninst;
    const int tid = threadIdx.x;

    float pres = 0.f;
    if (tid < B_*C_) pres = (ws[OFF_CNT + tid] > 0.f) ? 1.f : 0.f;
    red[tid] = pres;
    __syncthreads();
    for (int s = TPB/2; s > 0; s >>= 1) {
        if (tid < s) red[tid] += red[tid + s];
        __syncthreads();
    }
    if (tid == 0) s_ninst = red[0];
    __syncthreads();
    const float n_inst = s_ninst;

    for (int i = tid; i < B_*C_*N_; i += TPB) {
        const int bc = i / N_;
        const float cnt = ws[OFF_CNT + bc];
        ws[OFF_CEN + i] = ws[OFF_SUMS + i] / fmaxf(cnt, 1.f);
    }
    for (int i = tid; i < B_*C_; i += TPB) {
        const float cnt = ws[OFF_CNT + i];
        ws[OFF_W + i] = (cnt > 0.f && n_inst > 0.f)
                        ? 1.0f / (fmaxf(cnt, 1.f) * fmaxf(n_inst, 1.f)) : 0.f;
    }
    __syncthreads();

    float psum = 0.f, pcnt = 0.f;
    for (int idx = tid; idx < B_*C_*C_; idx += TPB) {
        const int b   = idx / (C_*C_);
        const int rem = idx % (C_*C_);
        const int i = rem / C_, j = rem % C_;
        if (i == j) continue;
        const float ci = ws[OFF_CNT + b*C_ + i];
        const float cj = ws[OFF_CNT + b*C_ + j];
        if (ci > 0.f && cj > 0.f) {
            float sq = 0.f;
            #pragma unroll
            for (int n = 0; n < N_; ++n) {
                const float d = ws[OFF_CEN + (b*C_ + i)*N_ + n]
                              - ws[OFF_CEN + (b*C_ + j)*N_ + n];
                sq += d * d;
            }
            const float pd = (sq > 0.f) ? sqrtf(sq) : 0.f;
            psum += fmaxf(2.f * MARGIN_DIST_ - pd, 0.f);
            pcnt += 1.f;
        }
    }
    red[tid] = psum;
    __syncthreads();
    for (int s = TPB/2; s > 0; s >>= 1) {
        if (tid < s) red[tid] += red[tid + s];
        __syncthreads();
    }
    const float tot_push = red[0];
    __syncthreads();
    red[tid] = pcnt;
    __syncthreads();
    for (int s = TPB/2; s > 0; s >>= 1) {
        if (tid < s) red[tid] += red[tid + s];
        __syncthreads();
    }
    if (tid == 0) {
        const float np = red[0];
        out[0] = (np > 0.f) ? tot_push / np : 0.f;   // DIST_WEIGHT = 1
    }
}

// ---------------------------------------------------------------------------
// Kernel 3: pull loss — 1024 px/block, one int4-label + 16 float4 loads/thread
// ---------------------------------------------------------------------------
__global__ __launch_bounds__(TPB) void k_pull(const float* __restrict__ feat,
                                              const int* __restrict__ gt,
                                              const float* __restrict__ ws,
                                              float* __restrict__ out) {
    __shared__ float s_cen[C_][N_ + 1];   // padded
    __shared__ float s_w[C_];
    __shared__ float wsum[TPB / 64];

    const int b     = blockIdx.x / BPI;
    const int chunk = blockIdx.x % BPI;
    const int base  = chunk * CHUNK;
    const int tid   = threadIdx.x;

    for (int i = tid; i < C_*N_; i += TPB)
        s_cen[i / N_][i % N_] = ws[OFF_CEN + b*C_*N_ + i];
    if (tid < C_) s_w[tid] = ws[OFF_W + b*C_ + tid];
    __syncthreads();

    const float* __restrict__ fb = feat + (size_t)b * N_ * P_ + base;
    const int*   __restrict__ gb = gt   + (size_t)b * P_ + base;

    const int4 lb = *(const int4*)(gb + tid * 4);
    const bool vx = (lb.x >= 1 && lb.x <= C_);
    const bool vy = (lb.y >= 1 && lb.y <= C_);
    const bool vz = (lb.z >= 1 && lb.z <= C_);
    const bool vw = (lb.w >= 1 && lb.w <= C_);
    const int cx = vx ? lb.x - 1 : 0;
    const int cy = vy ? lb.y - 1 : 0;
    const int cz = vz ? lb.z - 1 : 0;
    const int cw = vw ? lb.w - 1 : 0;

    float sq0 = 0.f, sq1 = 0.f, sq2 = 0.f, sq3 = 0.f;
    #pragma unroll
    for (int n = 0; n < N_; ++n) {
        const float4 v = *(const float4*)(fb + (size_t)n * P_ + tid * 4);
        const float d0 = v.x - s_cen[cx][n];
        const float d1 = v.y - s_cen[cy][n];
        const float d2 = v.z - s_cen[cz][n];
        const float d3 = v.w - s_cen[cw][n];
        sq0 += d0 * d0; sq1 += d1 * d1; sq2 += d2 * d2; sq3 += d3 * d3;
    }
    float acc = 0.f;
    acc += fmaxf(sqrtf(sq0) - MARGIN_VAR_, 0.f) * (vx ? s_w[cx] : 0.f);
    acc += fmaxf(sqrtf(sq1) - MARGIN_VAR_, 0.f) * (vy ? s_w[cy] : 0.f);
    acc += fmaxf(sqrtf(sq2) - MARGIN_VAR_, 0.f) * (vz ? s_w[cz] : 0.f);
    acc += fmaxf(sqrtf(sq3) - MARGIN_VAR_, 0.f) * (vw ? s_w[cw] : 0.f);

    acc = wave_reduce(acc);
    const int lane = tid & 63, wid = tid >> 6;
    if (lane == 0) wsum[wid] = acc;
    __syncthreads();
    if (tid == 0) {
        float t = 0.f;
        #pragma unroll
        for (int w = 0; w < TPB/64; ++w) t += wsum[w];
        atomicAdd(out, t);   // VAR_WEIGHT = 1
    }
}

// ---------------------------------------------------------------------------
extern "C" void kernel_launch(void* const* d_in, const int* in_sizes, int n_in,
                              void* d_out, int out_size, void* d_ws, size_t ws_size,
                              hipStream_t stream) {
    const float* feat = (const float*)d_in[0];
    const int*   gt   = (const int*)d_in[1];
    float* out = (float*)d_out;
    float* ws  = (float*)d_ws;

    hipMemsetAsync(d_ws, 0, WS_FLOATS * sizeof(float), stream);

    k_accum<<<dim3(B_ * BPI * CG), dim3(TPB), 0, stream>>>(feat, gt, ws);
    k_centers_push<<<dim3(1), dim3(TPB), 0, stream>>>(ws, out);
    k_pull<<<dim3(B_ * BPI), dim3(TPB), 0, stream>>>(feat, gt, ws, out);
}

// Round 4
// 131.896 us; speedup vs baseline: 2.0959x; 2.0959x over previous
//
#include <hip/hip_runtime.h>

// Problem constants (fixed by reference setup_inputs)
constexpr int B_ = 8;
constexpr int N_ = 16;
constexpr int H_ = 368;
constexpr int W_ = 640;
constexpr int P_ = H_ * W_;          // 235520 pixels per image
constexpr int C_ = 12;               // instance ids 1..12
constexpr float MARGIN_VAR_ = 0.5f;
constexpr float MARGIN_DIST_ = 3.0f;

// Workspace layout (floats): only sums + counts now
constexpr int OFF_SUMS = 0;                      // [B][C][N] feature sums
constexpr int OFF_CNT  = OFF_SUMS + B_*C_*N_;    // [B][C]    pixel counts
constexpr int WS_FLOATS = OFF_CNT + B_*C_;       // 1632 floats

constexpr int TPB = 256;

constexpr int ACHUNK = 2048;           // k_accum pixels per block
constexpr int ABPI   = P_ / ACHUNK;    // 115 (exact)
constexpr int PCHUNK = 1024;           // k_pull pixels per block
constexpr int PBPI   = P_ / PCHUNK;    // 230 (exact)

__device__ __forceinline__ float wave_reduce(float a) {
    #pragma unroll
    for (int off = 32; off > 0; off >>= 1) a += __shfl_down(a, off, 64);
    return a;
}

// ---------------------------------------------------------------------------
// Kernel 1: per-class feature sums + counts.
// Block = 2048 pixels; labels staged once in LDS; each wave owns 4 channels.
// Per channel: 8 independent float4 loads issued as a batch (MLP), then
// register compare-select accumulation, wave-reduce, one atomic per (c,n).
// ---------------------------------------------------------------------------
__global__ __launch_bounds__(TPB, 4) void k_accum(const float* __restrict__ feat,
                                                  const int* __restrict__ gt,
                                                  float* __restrict__ ws,
                                                  float* __restrict__ out) {
    __shared__ int4  s_lab4[ACHUNK / 4];    // 512 int4 = 8 KB
    __shared__ float s_red[TPB / 64][C_];

    const int tid  = threadIdx.x;
    const int lane = tid & 63, wid = tid >> 6;
    const int b     = blockIdx.x / ABPI;
    const int chunk = blockIdx.x % ABPI;
    const int base  = chunk * ACHUNK;

    if (blockIdx.x == 0 && tid == 0) out[0] = 0.f;   // init output (runs before k_pull)

    const int*   __restrict__ gb = gt   + (size_t)b * P_ + base;
    const float* __restrict__ fb = feat + (size_t)b * N_ * P_ + base;

    // stage 2048 labels (2 int4 per thread) + per-class counts in registers
    const int4 la = *(const int4*)(gb + tid * 8);
    const int4 lc = *(const int4*)(gb + tid * 8 + 4);
    s_lab4[2 * tid]     = la;
    s_lab4[2 * tid + 1] = lc;

    float cnt[C_];
    #pragma unroll
    for (int c = 0; c < C_; ++c) cnt[c] = 0.f;
    #pragma unroll
    for (int c = 0; c < C_; ++c) {
        cnt[c] += (la.x == c + 1) ? 1.f : 0.f;
        cnt[c] += (la.y == c + 1) ? 1.f : 0.f;
        cnt[c] += (la.z == c + 1) ? 1.f : 0.f;
        cnt[c] += (la.w == c + 1) ? 1.f : 0.f;
        cnt[c] += (lc.x == c + 1) ? 1.f : 0.f;
        cnt[c] += (lc.y == c + 1) ? 1.f : 0.f;
        cnt[c] += (lc.z == c + 1) ? 1.f : 0.f;
        cnt[c] += (lc.w == c + 1) ? 1.f : 0.f;
    }
    #pragma unroll
    for (int c = 0; c < C_; ++c) {
        const float r = wave_reduce(cnt[c]);
        if (lane == 0) s_red[wid][c] = r;
    }
    __syncthreads();
    if (tid < C_) {
        float t = 0.f;
        #pragma unroll
        for (int w = 0; w < TPB / 64; ++w) t += s_red[w][tid];
        atomicAdd(&ws[OFF_CNT + b * C_ + tid], t);
    }

    // per-wave channels: n = wid*4 + nc
    #pragma unroll 2
    for (int nc = 0; nc < 4; ++nc) {
        const int n = wid * 4 + nc;
        const float* __restrict__ fp = fb + (size_t)n * P_;

        // batch-issue 8 independent float4 loads (covers 2048 px / wave)
        float4 v[8];
        #pragma unroll
        for (int k = 0; k < 8; ++k)
            v[k] = *(const float4*)(fp + k * 256 + lane * 4);

        float acc[C_];
        #pragma unroll
        for (int c = 0; c < C_; ++c) acc[c] = 0.f;

        #pragma unroll
        for (int k = 0; k < 8; ++k) {
            const int4 L = s_lab4[k * 64 + lane];
            #pragma unroll
            for (int c = 0; c < C_; ++c) {
                acc[c] += (L.x == c + 1) ? v[k].x : 0.f;
                acc[c] += (L.y == c + 1) ? v[k].y : 0.f;
                acc[c] += (L.z == c + 1) ? v[k].z : 0.f;
                acc[c] += (L.w == c + 1) ? v[k].w : 0.f;
            }
        }
        #pragma unroll
        for (int c = 0; c < C_; ++c) {
            const float r = wave_reduce(acc[c]);
            if (lane == 0)
                atomicAdd(&ws[OFF_SUMS + ((size_t)b * C_ + c) * N_ + n], r);
        }
    }
}

// ---------------------------------------------------------------------------
// Kernel 2: pull loss + (chunk==0) push loss. Each block recomputes centers,
// weights, n_inst from the tiny sums/counts workspace; main feature loads are
// issued before the preamble so they are in flight during it.
// ---------------------------------------------------------------------------
__global__ __launch_bounds__(TPB, 4) void k_pull(const float* __restrict__ feat,
                                                 const int* __restrict__ gt,
                                                 const float* __restrict__ ws,
                                                 float* __restrict__ out) {
    __shared__ float s_cen[C_][N_ + 1];
    __shared__ float s_w[C_];
    __shared__ float s_cntv[B_ * C_];
    __shared__ float red[TPB];
    __shared__ float wsum[TPB / 64];

    const int tid   = threadIdx.x;
    const int b     = blockIdx.x / PBPI;
    const int chunk = blockIdx.x % PBPI;
    const int base  = chunk * PCHUNK;

    // ---- issue main loads first (independent of preamble) ----
    const int4 lb = *(const int4*)(gt + (size_t)b * P_ + base + tid * 4);
    float4 v[N_];
    #pragma unroll
    for (int n = 0; n < N_; ++n)
        v[n] = *(const float4*)(feat + ((size_t)b * N_ + n) * P_ + base + tid * 4);

    // ---- preamble: counts -> n_inst, centers, weights ----
    if (tid < B_ * C_) s_cntv[tid] = ws[OFF_CNT + tid];
    __syncthreads();
    red[tid] = (tid < B_ * C_ && s_cntv[tid] > 0.f) ? 1.f : 0.f;
    __syncthreads();
    for (int s = TPB / 2; s > 0; s >>= 1) {
        if (tid < s) red[tid] += red[tid + s];
        __syncthreads();
    }
    const float n_inst = red[0];
    __syncthreads();   // before red[] reuse below (push path)

    if (tid < C_ * N_) {
        const int c = tid >> 4, n = tid & 15;
        const float ct = s_cntv[b * C_ + c];
        s_cen[c][n] = ws[OFF_SUMS + ((size_t)b * C_ + c) * N_ + n] / fmaxf(ct, 1.f);
    }
    if (tid < C_) {
        const float ct = s_cntv[b * C_ + tid];
        s_w[tid] = (ct > 0.f && n_inst > 0.f) ? 1.0f / (ct * n_inst) : 0.f;
    }
    __syncthreads();

    // ---- push loss: only the chunk==0 block of each image ----
    if (chunk == 0) {
        float ps = 0.f;
        if (tid < C_ * C_) {
            const int i = tid / C_, j = tid % C_;
            if (i != j && s_cntv[b * C_ + i] > 0.f && s_cntv[b * C_ + j] > 0.f) {
                float sq = 0.f;
                #pragma unroll
                for (int n = 0; n < N_; ++n) {
                    const float d = s_cen[i][n] - s_cen[j][n];
                    sq += d * d;
                }
                ps = fmaxf(2.f * MARGIN_DIST_ - sqrtf(sq), 0.f);
            }
        }
        red[tid] = ps;
        __syncthreads();
        for (int s = TPB / 2; s > 0; s >>= 1) {
            if (tid < s) red[tid] += red[tid + s];
            __syncthreads();
        }
        if (tid == 0) {
            float np = 0.f;
            for (int bb = 0; bb < B_; ++bb) {
                int k = 0;
                for (int c = 0; c < C_; ++c) k += (s_cntv[bb * C_ + c] > 0.f) ? 1 : 0;
                np += (float)(k * (k - 1));
            }
            if (np > 0.f) atomicAdd(out, red[0] / np);   // DIST_WEIGHT = 1
        }
    }

    // ---- pull main: 4 pixels per thread ----
    const bool vx = (lb.x >= 1 && lb.x <= C_);
    const bool vy = (lb.y >= 1 && lb.y <= C_);
    const bool vz = (lb.z >= 1 && lb.z <= C_);
    const bool vw = (lb.w >= 1 && lb.w <= C_);
    const int cx = vx ? lb.x - 1 : 0;
    const int cy = vy ? lb.y - 1 : 0;
    const int cz = vz ? lb.z - 1 : 0;
    const int cw = vw ? lb.w - 1 : 0;

    float sq0 = 0.f, sq1 = 0.f, sq2 = 0.f, sq3 = 0.f;
    #pragma unroll
    for (int n = 0; n < N_; ++n) {
        const float d0 = v[n].x - s_cen[cx][n];
        const float d1 = v[n].y - s_cen[cy][n];
        const float d2 = v[n].z - s_cen[cz][n];
        const float d3 = v[n].w - s_cen[cw][n];
        sq0 += d0 * d0; sq1 += d1 * d1; sq2 += d2 * d2; sq3 += d3 * d3;
    }
    float acc = 0.f;
    acc += fmaxf(sqrtf(sq0) - MARGIN_VAR_, 0.f) * (vx ? s_w[cx] : 0.f);
    acc += fmaxf(sqrtf(sq1) - MARGIN_VAR_, 0.f) * (vy ? s_w[cy] : 0.f);
    acc += fmaxf(sqrtf(sq2) - MARGIN_VAR_, 0.f) * (vz ? s_w[cz] : 0.f);
    acc += fmaxf(sqrtf(sq3) - MARGIN_VAR_, 0.f) * (vw ? s_w[cw] : 0.f);

    acc = wave_reduce(acc);
    const int lane = tid & 63, wid = tid >> 6;
    if (lane == 0) wsum[wid] = acc;
    __syncthreads();
    if (tid == 0) {
        float t = 0.f;
        #pragma unroll
        for (int w = 0; w < TPB / 64; ++w) t += wsum[w];
        atomicAdd(out, t);   // VAR_WEIGHT = 1
    }
}

// ---------------------------------------------------------------------------
extern "C" void kernel_launch(void* const* d_in, const int* in_sizes, int n_in,
                              void* d_out, int out_size, void* d_ws, size_t ws_size,
                              hipStream_t stream) {
    const float* feat = (const float*)d_in[0];
    const int*   gt   = (const int*)d_in[1];
    float* out = (float*)d_out;
    float* ws  = (float*)d_ws;

    hipMemsetAsync(d_ws, 0, WS_FLOATS * sizeof(float), stream);

    k_accum<<<dim3(B_ * ABPI), dim3(TPB), 0, stream>>>(feat, gt, ws, out);
    k_pull <<<dim3(B_ * PBPI), dim3(TPB), 0, stream>>>(feat, gt, ws, out);
}

// Round 5
// 91.126 us; speedup vs baseline: 3.0336x; 1.4474x over previous
//
#include <hip/hip_runtime.h>

// Problem constants (fixed by reference setup_inputs)
constexpr int B_ = 8;
constexpr int N_ = 16;
constexpr int H_ = 368;
constexpr int W_ = 640;
constexpr int P_ = H_ * W_;          // 235520 pixels per image
constexpr int C_ = 12;               // instance ids 1..12
constexpr float MARGIN_VAR_ = 0.5f;
constexpr float MARGIN_DIST_ = 3.0f;

// Workspace layout (floats): sums + counts
constexpr int OFF_SUMS = 0;                      // [B][C][N] feature sums
constexpr int OFF_CNT  = OFF_SUMS + B_*C_*N_;    // [B][C]    pixel counts
constexpr int WS_FLOATS = OFF_CNT + B_*C_;       // 1632 floats

constexpr int TPB = 256;

constexpr int ACHUNK = 2048;           // k_accum pixels per block
constexpr int ABPI   = P_ / ACHUNK;    // 115 (exact)
constexpr int PCHUNK = 1024;           // k_pull pixels per block
constexpr int PBPI   = P_ / PCHUNK;    // 230 (exact)

// ---------------------------------------------------------------------------
// Kernel 1: per-class feature sums + counts.
// Block = 2048 px, 4 waves; each wave owns 4 channels over the whole chunk.
// Inner loop: per int4 of labels compute 12 masks ONCE, reuse as v_fmac
// across the wave's 4 channels (~15 VALU ops/element vs 36 before).
// One-iteration register rotate keeps 4 float4 loads + 1 ds_read in flight.
// ---------------------------------------------------------------------------
__global__ __launch_bounds__(TPB) void k_accum(const float* __restrict__ feat,
                                               const int* __restrict__ gt,
                                               float* __restrict__ ws,
                                               float* __restrict__ out) {
    __shared__ int4  s_lab4[ACHUNK / 4];    // 512 int4 = 8 KB
    __shared__ float s_red[4][C_];
    __shared__ float s_fin[4][48];

    const int tid  = threadIdx.x;
    const int lane = tid & 63, wid = tid >> 6;
    const int b     = blockIdx.x / ABPI;
    const int chunk = blockIdx.x % ABPI;
    const int base  = chunk * ACHUNK;

    if (blockIdx.x == 0 && tid == 0) out[0] = 0.f;   // init output before k_pull

    const int*   __restrict__ gb = gt   + (size_t)b * P_ + base;
    const float* __restrict__ fb = feat + (size_t)b * N_ * P_ + base;

    // ---- stage labels (2 int4/thread) + per-thread counts (each pixel once) ----
    const int4 la = *(const int4*)(gb + tid * 8);
    const int4 lc = *(const int4*)(gb + tid * 8 + 4);
    s_lab4[2 * tid]     = la;
    s_lab4[2 * tid + 1] = lc;

    float cnt[C_];
    #pragma unroll
    for (int c = 0; c < C_; ++c) {
        cnt[c] = ((la.x == c+1) ? 1.f : 0.f) + ((la.y == c+1) ? 1.f : 0.f)
               + ((la.z == c+1) ? 1.f : 0.f) + ((la.w == c+1) ? 1.f : 0.f)
               + ((lc.x == c+1) ? 1.f : 0.f) + ((lc.y == c+1) ? 1.f : 0.f)
               + ((lc.z == c+1) ? 1.f : 0.f) + ((lc.w == c+1) ? 1.f : 0.f);
    }
    // stage-outer butterfly (12 independent chains per stage)
    #pragma unroll
    for (int off = 32; off > 0; off >>= 1) {
        #pragma unroll
        for (int c = 0; c < C_; ++c) cnt[c] += __shfl_xor(cnt[c], off, 64);
    }
    if (lane == 0) {
        #pragma unroll
        for (int c = 0; c < C_; ++c) s_red[wid][c] = cnt[c];
    }
    __syncthreads();
    if (tid < C_) {
        const float t = s_red[0][tid] + s_red[1][tid] + s_red[2][tid] + s_red[3][tid];
        atomicAdd(&ws[OFF_CNT + b * C_ + tid], t);
    }

    // ---- main: wave owns channels n0..n0+3 over all 2048 pixels ----
    const int n0 = wid * 4;
    const float* __restrict__ fp0 = fb + (size_t)(n0 + 0) * P_;
    const float* __restrict__ fp1 = fb + (size_t)(n0 + 1) * P_;
    const float* __restrict__ fp2 = fb + (size_t)(n0 + 2) * P_;
    const float* __restrict__ fp3 = fb + (size_t)(n0 + 3) * P_;

    float acc[4][C_];
    #pragma unroll
    for (int nc = 0; nc < 4; ++nc)
        #pragma unroll
        for (int c = 0; c < C_; ++c) acc[nc][c] = 0.f;

    // prefetch k = 0
    int4   L  = s_lab4[lane];
    float4 v0 = *(const float4*)(fp0 + lane * 4);
    float4 v1 = *(const float4*)(fp1 + lane * 4);
    float4 v2 = *(const float4*)(fp2 + lane * 4);
    float4 v3 = *(const float4*)(fp3 + lane * 4);

    #pragma unroll
    for (int k = 0; k < 8; ++k) {
        int4 Ln; float4 w0, w1, w2, w3;
        if (k < 7) {   // static under full unroll
            const int idx = (k + 1) * 64 + lane;
            Ln = s_lab4[idx];
            w0 = *(const float4*)(fp0 + idx * 4);
            w1 = *(const float4*)(fp1 + idx * 4);
            w2 = *(const float4*)(fp2 + idx * 4);
            w3 = *(const float4*)(fp3 + idx * 4);
        }
        float m[C_];
        // pixel .x
        #pragma unroll
        for (int c = 0; c < C_; ++c) m[c] = (L.x == c + 1) ? 1.f : 0.f;
        #pragma unroll
        for (int c = 0; c < C_; ++c) {
            acc[0][c] += m[c] * v0.x; acc[1][c] += m[c] * v1.x;
            acc[2][c] += m[c] * v2.x; acc[3][c] += m[c] * v3.x;
        }
        // pixel .y
        #pragma unroll
        for (int c = 0; c < C_; ++c) m[c] = (L.y == c + 1) ? 1.f : 0.f;
        #pragma unroll
        for (int c = 0; c < C_; ++c) {
            acc[0][c] += m[c] * v0.y; acc[1][c] += m[c] * v1.y;
            acc[2][c] += m[c] * v2.y; acc[3][c] += m[c] * v3.y;
        }
        // pixel .z
        #pragma unroll
        for (int c = 0; c < C_; ++c) m[c] = (L.z == c + 1) ? 1.f : 0.f;
        #pragma unroll
        for (int c = 0; c < C_; ++c) {
            acc[0][c] += m[c] * v0.z; acc[1][c] += m[c] * v1.z;
            acc[2][c] += m[c] * v2.z; acc[3][c] += m[c] * v3.z;
        }
        // pixel .w
        #pragma unroll
        for (int c = 0; c < C_; ++c) m[c] = (L.w == c + 1) ? 1.f : 0.f;
        #pragma unroll
        for (int c = 0; c < C_; ++c) {
            acc[0][c] += m[c] * v0.w; acc[1][c] += m[c] * v1.w;
            acc[2][c] += m[c] * v2.w; acc[3][c] += m[c] * v3.w;
        }
        L = Ln; v0 = w0; v1 = w1; v2 = w2; v3 = w3;
    }

    // ---- finale: stage-outer butterfly over 48 values, then 192 atomics/block ----
    #pragma unroll
    for (int off = 32; off > 0; off >>= 1) {
        #pragma unroll
        for (int nc = 0; nc < 4; ++nc)
            #pragma unroll
            for (int c = 0; c < C_; ++c)
                acc[nc][c] += __shfl_xor(acc[nc][c], off, 64);
    }
    if (lane == 0) {
        #pragma unroll
        for (int nc = 0; nc < 4; ++nc)
            #pragma unroll
            for (int c = 0; c < C_; ++c) s_fin[wid][nc * C_ + c] = acc[nc][c];
    }
    __syncthreads();
    if (tid < 4 * 48) {
        const int wsrc = tid / 48, rem = tid % 48;
        const int nc = rem / C_, c = rem % C_;
        const int n = wsrc * 4 + nc;
        atomicAdd(&ws[OFF_SUMS + ((size_t)b * C_ + c) * N_ + n], s_fin[wsrc][rem]);
    }
}

// ---------------------------------------------------------------------------
// Kernel 2: pull loss + (chunk==0) push loss. Each block recomputes centers,
// weights, n_inst from the tiny sums/counts workspace; main feature loads are
// issued before the preamble so they are in flight during it.
// ---------------------------------------------------------------------------
__global__ __launch_bounds__(TPB) void k_pull(const float* __restrict__ feat,
                                              const int* __restrict__ gt,
                                              const float* __restrict__ ws,
                                              float* __restrict__ out) {
    __shared__ float s_cen[C_][N_ + 1];
    __shared__ float s_w[C_];
    __shared__ float s_cntv[B_ * C_];
    __shared__ float red[TPB];
    __shared__ float wsum[TPB / 64];

    const int tid   = threadIdx.x;
    const int b     = blockIdx.x / PBPI;
    const int chunk = blockIdx.x % PBPI;
    const int base  = chunk * PCHUNK;

    // ---- issue main loads first (independent of preamble) ----
    const int4 lb = *(const int4*)(gt + (size_t)b * P_ + base + tid * 4);
    float4 v[N_];
    #pragma unroll
    for (int n = 0; n < N_; ++n)
        v[n] = *(const float4*)(feat + ((size_t)b * N_ + n) * P_ + base + tid * 4);

    // ---- preamble: counts -> n_inst, centers, weights ----
    if (tid < B_ * C_) s_cntv[tid] = ws[OFF_CNT + tid];
    __syncthreads();
    red[tid] = (tid < B_ * C_ && s_cntv[tid] > 0.f) ? 1.f : 0.f;
    __syncthreads();
    for (int s = TPB / 2; s > 0; s >>= 1) {
        if (tid < s) red[tid] += red[tid + s];
        __syncthreads();
    }
    const float n_inst = red[0];
    __syncthreads();   // before red[] reuse below (push path)

    if (tid < C_ * N_) {
        const int c = tid >> 4, n = tid & 15;
        const float ct = s_cntv[b * C_ + c];
        s_cen[c][n] = ws[OFF_SUMS + ((size_t)b * C_ + c) * N_ + n] / fmaxf(ct, 1.f);
    }
    if (tid < C_) {
        const float ct = s_cntv[b * C_ + tid];
        s_w[tid] = (ct > 0.f && n_inst > 0.f) ? 1.0f / (ct * n_inst) : 0.f;
    }
    __syncthreads();

    // ---- push loss: only the chunk==0 block of each image ----
    if (chunk == 0) {
        float ps = 0.f;
        if (tid < C_ * C_) {
            const int i = tid / C_, j = tid % C_;
            if (i != j && s_cntv[b * C_ + i] > 0.f && s_cntv[b * C_ + j] > 0.f) {
                float sq = 0.f;
                #pragma unroll
                for (int n = 0; n < N_; ++n) {
                    const float d = s_cen[i][n] - s_cen[j][n];
                    sq += d * d;
                }
                ps = fmaxf(2.f * MARGIN_DIST_ - sqrtf(sq), 0.f);
            }
        }
        red[tid] = ps;
        __syncthreads();
        for (int s = TPB / 2; s > 0; s >>= 1) {
            if (tid < s) red[tid] += red[tid + s];
            __syncthreads();
        }
        if (tid == 0) {
            float np = 0.f;
            for (int bb = 0; bb < B_; ++bb) {
                int k = 0;
                for (int c = 0; c < C_; ++c) k += (s_cntv[bb * C_ + c] > 0.f) ? 1 : 0;
                np += (float)(k * (k - 1));
            }
            if (np > 0.f) atomicAdd(out, red[0] / np);   // DIST_WEIGHT = 1
        }
    }

    // ---- pull main: 4 pixels per thread ----
    const bool vx = (lb.x >= 1 && lb.x <= C_);
    const bool vy = (lb.y >= 1 && lb.y <= C_);
    const bool vz = (lb.z >= 1 && lb.z <= C_);
    const bool vw = (lb.w >= 1 && lb.w <= C_);
    const int cx = vx ? lb.x - 1 : 0;
    const int cy = vy ? lb.y - 1 : 0;
    const int cz = vz ? lb.z - 1 : 0;
    const int cw = vw ? lb.w - 1 : 0;

    float sq0 = 0.f, sq1 = 0.f, sq2 = 0.f, sq3 = 0.f;
    #pragma unroll
    for (int n = 0; n < N_; ++n) {
        const float d0 = v[n].x - s_cen[cx][n];
        const float d1 = v[n].y - s_cen[cy][n];
        const float d2 = v[n].z - s_cen[cz][n];
        const float d3 = v[n].w - s_cen[cw][n];
        sq0 += d0 * d0; sq1 += d1 * d1; sq2 += d2 * d2; sq3 += d3 * d3;
    }
    float acc = 0.f;
    acc += fmaxf(sqrtf(sq0) - MARGIN_VAR_, 0.f) * (vx ? s_w[cx] : 0.f);
    acc += fmaxf(sqrtf(sq1) - MARGIN_VAR_, 0.f) * (vy ? s_w[cy] : 0.f);
    acc += fmaxf(sqrtf(sq2) - MARGIN_VAR_, 0.f) * (vz ? s_w[cz] : 0.f);
    acc += fmaxf(sqrtf(sq3) - MARGIN_VAR_, 0.f) * (vw ? s_w[cw] : 0.f);

    #pragma unroll
    for (int off = 32; off > 0; off >>= 1) acc += __shfl_down(acc, off, 64);
    const int lane = tid & 63, wid = tid >> 6;
    if (lane == 0) wsum[wid] = acc;
    __syncthreads();
    if (tid == 0) {
        float t = 0.f;
        #pragma unroll
        for (int w = 0; w < TPB / 64; ++w) t += wsum[w];
        atomicAdd(out, t);   // VAR_WEIGHT = 1
    }
}

// ---------------------------------------------------------------------------
extern "C" void kernel_launch(void* const* d_in, const int* in_sizes, int n_in,
                              void* d_out, int out_size, void* d_ws, size_t ws_size,
                              hipStream_t stream) {
    const float* feat = (const float*)d_in[0];
    const int*   gt   = (const int*)d_in[1];
    float* out = (float*)d_out;
    float* ws  = (float*)d_ws;

    hipMemsetAsync(d_ws, 0, WS_FLOATS * sizeof(float), stream);

    k_accum<<<dim3(B_ * ABPI), dim3(TPB), 0, stream>>>(feat, gt, ws, out);
    k_pull <<<dim3(B_ * PBPI), dim3(TPB), 0, stream>>>(feat, gt, ws, out);
}

// Round 6
// 70.855 us; speedup vs baseline: 3.9016x; 1.2861x over previous
//
#include <hip/hip_runtime.h>
#include <hip/hip_bf16.h>

// Problem constants (fixed by reference setup_inputs)
constexpr int B_ = 8;
constexpr int N_ = 16;
constexpr int H_ = 368;
constexpr int W_ = 640;
constexpr int P_ = H_ * W_;          // 235520 pixels per image
constexpr int C_ = 12;               // instance ids 1..12
constexpr float MARGIN_VAR_ = 0.5f;
constexpr float MARGIN_DIST_ = 3.0f;

// Workspace layout (floats): sums + counts
constexpr int OFF_SUMS = 0;                      // [B][C][N] feature sums
constexpr int OFF_CNT  = OFF_SUMS + B_*C_*N_;    // [B][C]    pixel counts
constexpr int WS_FLOATS = OFF_CNT + B_*C_;       // 1632 floats

constexpr int TPB = 256;

constexpr int MCHUNK = 1024;           // k_accum pixels per block
constexpr int MBPI   = P_ / MCHUNK;    // 230 (exact)
constexpr int PCHUNK = 1024;           // k_pull pixels per block
constexpr int PBPI   = P_ / PCHUNK;    // 230 (exact)

typedef short bf16x8 __attribute__((ext_vector_type(8)));   // 8 bf16 (4 VGPR)
typedef float f32x4  __attribute__((ext_vector_type(4)));   // MFMA accumulator

__device__ __forceinline__ short f2bf(float f) {
    __hip_bfloat16 h = __float2bfloat16(f);
    return __builtin_bit_cast(short, h);
}

// ---------------------------------------------------------------------------
// Kernel 1: per-class feature sums + counts via MFMA.
// sums[c][n] = sum_p mask[c][p] * feat[n][p]  ==  A(16x32 masks) x B(32x16 feat)
// per 32-pixel chunk, accumulated in f32x4 AGPRs. Masks exact in bf16 (0/1);
// feat rounded to bf16 (center error ~1e-5, far below threshold).
// Lane roles: class = (lane&15)+1 for A; channel = lane&15 for B;
// k-octet = (lane>>4)*8 for both. Depth-2 global load pipeline.
// ---------------------------------------------------------------------------
__global__ __launch_bounds__(TPB) void k_accum(const float* __restrict__ feat,
                                               const int* __restrict__ gt,
                                               float* __restrict__ ws,
                                               float* __restrict__ out) {
    __shared__ int   s_lab[MCHUNK];        // 4 KB
    __shared__ float s_red[4][C_];
    __shared__ float s_fin[4][256];        // 4 KB: per-wave D elements

    const int tid  = threadIdx.x;
    const int lane = tid & 63, wid = tid >> 6;
    const int b     = blockIdx.x / MBPI;
    const int chunk = blockIdx.x % MBPI;
    const int base  = chunk * MCHUNK;

    if (blockIdx.x == 0 && tid == 0) out[0] = 0.f;   // init output before k_pull

    const int*   __restrict__ gb = gt   + (size_t)b * P_ + base;
    const float* __restrict__ fb = feat + (size_t)b * N_ * P_ + base;

    // ---- stage labels (1 int4/thread) + per-class counts ----
    const int4 la = ((const int4*)gb)[tid];
    ((int4*)s_lab)[tid] = la;

    float cnt[C_];
    #pragma unroll
    for (int c = 0; c < C_; ++c) {
        cnt[c] = ((la.x == c+1) ? 1.f : 0.f) + ((la.y == c+1) ? 1.f : 0.f)
               + ((la.z == c+1) ? 1.f : 0.f) + ((la.w == c+1) ? 1.f : 0.f);
    }
    #pragma unroll
    for (int off = 32; off > 0; off >>= 1) {
        #pragma unroll
        for (int c = 0; c < C_; ++c) cnt[c] += __shfl_xor(cnt[c], off, 64);
    }
    if (lane == 0) {
        #pragma unroll
        for (int c = 0; c < C_; ++c) s_red[wid][c] = cnt[c];
    }
    __syncthreads();
    if (tid < C_) {
        const float t = s_red[0][tid] + s_red[1][tid] + s_red[2][tid] + s_red[3][tid];
        atomicAdd(&ws[OFF_CNT + b * C_ + tid], t);
    }

    // ---- MFMA main: wave covers 256 px = 8 chunks of 32 ----
    const int n     = lane & 15;            // channel (B col) / class-1 (A row)
    const int cls   = n + 1;
    const int ko    = (lane >> 4) * 8;      // k-octet within 32-px chunk
    const int wbase = wid * 256;
    const float* __restrict__ fp = fb + (size_t)n * P_;

    f32x4 acc = {0.f, 0.f, 0.f, 0.f};

    // depth-2 pipeline of the 8 f32 (2x dwordx4) feat loads per chunk
    float4 ra[2], rb[2];
    ra[0] = *(const float4*)(fp + wbase + 0 * 32 + ko);
    rb[0] = *(const float4*)(fp + wbase + 0 * 32 + ko + 4);
    ra[1] = *(const float4*)(fp + wbase + 1 * 32 + ko);
    rb[1] = *(const float4*)(fp + wbase + 1 * 32 + ko + 4);

    #pragma unroll
    for (int t = 0; t < 8; ++t) {
        const int s = t & 1;
        const float4 c0 = ra[s], c1 = rb[s];
        if (t < 6) {   // static under full unroll
            ra[s] = *(const float4*)(fp + wbase + (t + 2) * 32 + ko);
            rb[s] = *(const float4*)(fp + wbase + (t + 2) * 32 + ko + 4);
        }
        // labels for this k-octet (LDS broadcast within each 16-lane group)
        const int* lp = s_lab + wbase + t * 32 + ko;
        const int4 L0 = *(const int4*)(lp);
        const int4 L1 = *(const int4*)(lp + 4);

        bf16x8 afrag, bfrag;
        afrag[0] = (L0.x == cls) ? (short)0x3F80 : (short)0;
        afrag[1] = (L0.y == cls) ? (short)0x3F80 : (short)0;
        afrag[2] = (L0.z == cls) ? (short)0x3F80 : (short)0;
        afrag[3] = (L0.w == cls) ? (short)0x3F80 : (short)0;
        afrag[4] = (L1.x == cls) ? (short)0x3F80 : (short)0;
        afrag[5] = (L1.y == cls) ? (short)0x3F80 : (short)0;
        afrag[6] = (L1.z == cls) ? (short)0x3F80 : (short)0;
        afrag[7] = (L1.w == cls) ? (short)0x3F80 : (short)0;

        bfrag[0] = f2bf(c0.x); bfrag[1] = f2bf(c0.y);
        bfrag[2] = f2bf(c0.z); bfrag[3] = f2bf(c0.w);
        bfrag[4] = f2bf(c1.x); bfrag[5] = f2bf(c1.y);
        bfrag[6] = f2bf(c1.z); bfrag[7] = f2bf(c1.w);

        acc = __builtin_amdgcn_mfma_f32_16x16x32_bf16(afrag, bfrag, acc, 0, 0, 0);
    }

    // ---- cross-wave reduce of D, then one atomic per (class,channel) ----
    #pragma unroll
    for (int r = 0; r < 4; ++r) s_fin[wid][lane * 4 + r] = acc[r];
    __syncthreads();

    {   // element e = tid: lane = e>>2, reg = e&3
        const float sv = s_fin[0][tid] + s_fin[1][tid] + s_fin[2][tid] + s_fin[3][tid];
        const int elane = tid >> 2, r = tid & 3;
        const int row = (elane >> 4) * 4 + r;   // class (D row)
        const int col = elane & 15;             // channel (D col)
        if (row < C_)
            atomicAdd(&ws[OFF_SUMS + ((size_t)b * C_ + row) * N_ + col], sv);
    }
}

// ---------------------------------------------------------------------------
// Kernel 2: pull loss + (chunk==0) push loss. Each block recomputes centers,
// weights, n_inst from the tiny sums/counts workspace; main feature loads are
// issued before the preamble so they are in flight during it.
// ---------------------------------------------------------------------------
__global__ __launch_bounds__(TPB) void k_pull(const float* __restrict__ feat,
                                              const int* __restrict__ gt,
                                              const float* __restrict__ ws,
                                              float* __restrict__ out) {
    __shared__ float s_cen[C_][N_ + 1];
    __shared__ float s_w[C_];
    __shared__ float s_cntv[B_ * C_];
    __shared__ float red[TPB];
    __shared__ float wsum[TPB / 64];

    const int tid   = threadIdx.x;
    const int b     = blockIdx.x / PBPI;
    const int chunk = blockIdx.x % PBPI;
    const int base  = chunk * PCHUNK;

    // ---- issue main loads first (independent of preamble) ----
    const int4 lb = *(const int4*)(gt + (size_t)b * P_ + base + tid * 4);
    float4 v[N_];
    #pragma unroll
    for (int n = 0; n < N_; ++n)
        v[n] = *(const float4*)(feat + ((size_t)b * N_ + n) * P_ + base + tid * 4);

    // ---- preamble: counts -> n_inst, centers, weights ----
    if (tid < B_ * C_) s_cntv[tid] = ws[OFF_CNT + tid];
    __syncthreads();
    red[tid] = (tid < B_ * C_ && s_cntv[tid] > 0.f) ? 1.f : 0.f;
    __syncthreads();
    for (int s = TPB / 2; s > 0; s >>= 1) {
        if (tid < s) red[tid] += red[tid + s];
        __syncthreads();
    }
    const float n_inst = red[0];
    __syncthreads();   // before red[] reuse below (push path)

    if (tid < C_ * N_) {
        const int c = tid >> 4, n = tid & 15;
        const float ct = s_cntv[b * C_ + c];
        s_cen[c][n] = ws[OFF_SUMS + ((size_t)b * C_ + c) * N_ + n] / fmaxf(ct, 1.f);
    }
    if (tid < C_) {
        const float ct = s_cntv[b * C_ + tid];
        s_w[tid] = (ct > 0.f && n_inst > 0.f) ? 1.0f / (ct * n_inst) : 0.f;
    }
    __syncthreads();

    // ---- push loss: only the chunk==0 block of each image ----
    if (chunk == 0) {
        float ps = 0.f;
        if (tid < C_ * C_) {
            const int i = tid / C_, j = tid % C_;
            if (i != j && s_cntv[b * C_ + i] > 0.f && s_cntv[b * C_ + j] > 0.f) {
                float sq = 0.f;
                #pragma unroll
                for (int n = 0; n < N_; ++n) {
                    const float d = s_cen[i][n] - s_cen[j][n];
                    sq += d * d;
                }
                ps = fmaxf(2.f * MARGIN_DIST_ - sqrtf(sq), 0.f);
            }
        }
        red[tid] = ps;
        __syncthreads();
        for (int s = TPB / 2; s > 0; s >>= 1) {
            if (tid < s) red[tid] += red[tid + s];
            __syncthreads();
        }
        if (tid == 0) {
            float np = 0.f;
            for (int bb = 0; bb < B_; ++bb) {
                int k = 0;
                for (int c = 0; c < C_; ++c) k += (s_cntv[bb * C_ + c] > 0.f) ? 1 : 0;
                np += (float)(k * (k - 1));
            }
            if (np > 0.f) atomicAdd(out, red[0] / np);   // DIST_WEIGHT = 1
        }
    }

    // ---- pull main: 4 pixels per thread ----
    const bool vx = (lb.x >= 1 && lb.x <= C_);
    const bool vy = (lb.y >= 1 && lb.y <= C_);
    const bool vz = (lb.z >= 1 && lb.z <= C_);
    const bool vw = (lb.w >= 1 && lb.w <= C_);
    const int cx = vx ? lb.x - 1 : 0;
    const int cy = vy ? lb.y - 1 : 0;
    const int cz = vz ? lb.z - 1 : 0;
    const int cw = vw ? lb.w - 1 : 0;

    float sq0 = 0.f, sq1 = 0.f, sq2 = 0.f, sq3 = 0.f;
    #pragma unroll
    for (int n = 0; n < N_; ++n) {
        const float d0 = v[n].x - s_cen[cx][n];
        const float d1 = v[n].y - s_cen[cy][n];
        const float d2 = v[n].z - s_cen[cz][n];
        const float d3 = v[n].w - s_cen[cw][n];
        sq0 += d0 * d0; sq1 += d1 * d1; sq2 += d2 * d2; sq3 += d3 * d3;
    }
    float acc = 0.f;
    acc += fmaxf(sqrtf(sq0) - MARGIN_VAR_, 0.f) * (vx ? s_w[cx] : 0.f);
    acc += fmaxf(sqrtf(sq1) - MARGIN_VAR_, 0.f) * (vy ? s_w[cy] : 0.f);
    acc += fmaxf(sqrtf(sq2) - MARGIN_VAR_, 0.f) * (vz ? s_w[cz] : 0.f);
    acc += fmaxf(sqrtf(sq3) - MARGIN_VAR_, 0.f) * (vw ? s_w[cw] : 0.f);

    #pragma unroll
    for (int off = 32; off > 0; off >>= 1) acc += __shfl_down(acc, off, 64);
    const int lane = tid & 63, wid = tid >> 6;
    if (lane == 0) wsum[wid] = acc;
    __syncthreads();
    if (tid == 0) {
        float t = 0.f;
        #pragma unroll
        for (int w = 0; w < TPB / 64; ++w) t += wsum[w];
        atomicAdd(out, t);   // VAR_WEIGHT = 1
    }
}

// ---------------------------------------------------------------------------
extern "C" void kernel_launch(void* const* d_in, const int* in_sizes, int n_in,
                              void* d_out, int out_size, void* d_ws, size_t ws_size,
                              hipStream_t stream) {
    const float* feat = (const float*)d_in[0];
    const int*   gt   = (const int*)d_in[1];
    float* out = (float*)d_out;
    float* ws  = (float*)d_ws;

    hipMemsetAsync(d_ws, 0, WS_FLOATS * sizeof(float), stream);

    k_accum<<<dim3(B_ * MBPI), dim3(TPB), 0, stream>>>(feat, gt, ws, out);
    k_pull <<<dim3(B_ * PBPI), dim3(TPB), 0, stream>>>(feat, gt, ws, out);
}

// Round 8
// 70.493 us; speedup vs baseline: 3.9216x; 1.0051x over previous
//
#include <hip/hip_runtime.h>
#include <hip/hip_bf16.h>

// Problem constants (fixed by reference setup_inputs)
constexpr int B_ = 8;
constexpr int N_ = 16;
constexpr int H_ = 368;
constexpr int W_ = 640;
constexpr int P_ = H_ * W_;          // 235520 pixels per image
constexpr int C_ = 12;               // instance ids 1..12
constexpr float MARGIN_VAR_ = 0.5f;
constexpr float MARGIN_DIST_ = 3.0f;

// Workspace layout (floats): sums + counts
constexpr int OFF_SUMS = 0;                      // [B][C][N] feature sums
constexpr int OFF_CNT  = OFF_SUMS + B_*C_*N_;    // [B][C]    pixel counts
constexpr int WS_FLOATS = OFF_CNT + B_*C_;       // 1632 floats

constexpr int TPB = 256;

constexpr int MCHUNK = 1024;           // k_accum pixels per block
constexpr int MBPI   = P_ / MCHUNK;    // 230 (exact)
constexpr int PCHUNK = 1024;           // k_pull pixels per block
constexpr int PBPI   = P_ / PCHUNK;    // 230 (exact)

typedef short bf16x8 __attribute__((ext_vector_type(8)));   // 8 bf16 (4 VGPR)
typedef float f32x4  __attribute__((ext_vector_type(4)));   // MFMA accumulator

union FragU { int4 i; bf16x8 v; };

__device__ __forceinline__ short f2bf(float f) {
    __hip_bfloat16 h = __float2bfloat16(f);
    return __builtin_bit_cast(short, h);
}

__device__ __forceinline__ int pack_bf2(float x, float y) {
    const unsigned lo = (unsigned short)f2bf(x);
    const unsigned hi = (unsigned short)f2bf(y);
    return (int)(lo | (hi << 16));
}

// ---------------------------------------------------------------------------
// Kernel 1: per-class feature sums + counts via MFMA.
// sums[c][n] = sum_p mask[c][p] * feat[n][p]  ==  A(16x32 masks) x B(32x16 feat)
// Lane roles: class=(lane&15)+1 for A; channel=lane&15 for B; k-octet=(lane>>4)*8.
// Depth-4 chunk pipeline (8 dwordx4 in flight); packed masks.
// ---------------------------------------------------------------------------
__global__ __launch_bounds__(TPB) void k_accum(const float* __restrict__ feat,
                                               const int* __restrict__ gt,
                                               float* __restrict__ ws,
                                               float* __restrict__ out) {
    __shared__ int   s_lab[MCHUNK];        // 4 KB
    __shared__ float s_red[4][C_];
    __shared__ float s_fin[4][256];        // 4 KB: per-wave D elements

    const int tid  = threadIdx.x;
    const int lane = tid & 63, wid = tid >> 6;
    const int b     = blockIdx.x / MBPI;
    const int chunk = blockIdx.x % MBPI;
    const int base  = chunk * MCHUNK;

    if (blockIdx.x == 0 && tid == 0) out[0] = 0.f;   // init output before k_pull

    const int*   __restrict__ gb = gt   + (size_t)b * P_ + base;
    const float* __restrict__ fb = feat + (size_t)b * N_ * P_ + base;

    // ---- stage labels (1 int4/thread) + per-class counts ----
    const int4 la = ((const int4*)gb)[tid];
    ((int4*)s_lab)[tid] = la;

    float cnt[C_];
    #pragma unroll
    for (int c = 0; c < C_; ++c) {
        cnt[c] = ((la.x == c+1) ? 1.f : 0.f) + ((la.y == c+1) ? 1.f : 0.f)
               + ((la.z == c+1) ? 1.f : 0.f) + ((la.w == c+1) ? 1.f : 0.f);
    }
    #pragma unroll
    for (int off = 32; off > 0; off >>= 1) {
        #pragma unroll
        for (int c = 0; c < C_; ++c) cnt[c] += __shfl_xor(cnt[c], off, 64);
    }
    if (lane == 0) {
        #pragma unroll
        for (int c = 0; c < C_; ++c) s_red[wid][c] = cnt[c];
    }
    __syncthreads();
    if (tid < C_) {
        const float t = s_red[0][tid] + s_red[1][tid] + s_red[2][tid] + s_red[3][tid];
        atomicAdd(&ws[OFF_CNT + b * C_ + tid], t);
    }

    // ---- MFMA main: wave covers 256 px = 8 chunks of 32 ----
    const int n     = lane & 15;            // channel (B col) / class-1 (A row)
    const int cls   = n + 1;
    const int ko    = (lane >> 4) * 8;      // k-octet within 32-px chunk
    const int wbase = wid * 256;
    const float* __restrict__ fp = fb + (size_t)n * P_;

    // depth-4 pipeline: 4 chunk buffers, 8 dwordx4 in flight
    float4 ba[4], bb[4];
    #pragma unroll
    for (int t = 0; t < 4; ++t) {
        ba[t] = *(const float4*)(fp + wbase + t * 32 + ko);
        bb[t] = *(const float4*)(fp + wbase + t * 32 + ko + 4);
    }

    f32x4 acc = {0.f, 0.f, 0.f, 0.f};

    #pragma unroll
    for (int t = 0; t < 8; ++t) {
        const float4 c0 = ba[t & 3], c1 = bb[t & 3];
        if (t < 4) {   // static under full unroll
            ba[t & 3] = *(const float4*)(fp + wbase + (t + 4) * 32 + ko);
            bb[t & 3] = *(const float4*)(fp + wbase + (t + 4) * 32 + ko + 4);
        }
        const int* lp = s_lab + wbase + t * 32 + ko;
        const int4 L0 = *(const int4*)(lp);
        const int4 L1 = *(const int4*)(lp + 4);

        FragU au, bu;
        au.i.x = ((L0.x == cls) ? 0x3F80 : 0) | ((L0.y == cls) ? 0x3F800000 : 0);
        au.i.y = ((L0.z == cls) ? 0x3F80 : 0) | ((L0.w == cls) ? 0x3F800000 : 0);
        au.i.z = ((L1.x == cls) ? 0x3F80 : 0) | ((L1.y == cls) ? 0x3F800000 : 0);
        au.i.w = ((L1.z == cls) ? 0x3F80 : 0) | ((L1.w == cls) ? 0x3F800000 : 0);

        bu.i.x = pack_bf2(c0.x, c0.y);
        bu.i.y = pack_bf2(c0.z, c0.w);
        bu.i.z = pack_bf2(c1.x, c1.y);
        bu.i.w = pack_bf2(c1.z, c1.w);

        acc = __builtin_amdgcn_mfma_f32_16x16x32_bf16(au.v, bu.v, acc, 0, 0, 0);
    }

    // ---- cross-wave reduce of D, then one atomic per (class,channel) ----
    #pragma unroll
    for (int r = 0; r < 4; ++r) s_fin[wid][lane * 4 + r] = acc[r];
    __syncthreads();

    {   // element e = tid: lane = e>>2, reg = e&3
        const float sv = s_fin[0][tid] + s_fin[1][tid] + s_fin[2][tid] + s_fin[3][tid];
        const int elane = tid >> 2, r = tid & 3;
        const int row = (elane >> 4) * 4 + r;   // class (D row)
        const int col = elane & 15;             // channel (D col)
        if (row < C_)
            atomicAdd(&ws[OFF_SUMS + ((size_t)b * C_ + row) * N_ + col], sv);
    }
}

// ---------------------------------------------------------------------------
// Kernel 2: pull loss + (chunk==0) push loss. Channel-group pipelined loads
// (2x4 float4 buffers) keep VGPR low for occupancy; n_inst via barrier-free
// per-thread LDS broadcast scan.
// ---------------------------------------------------------------------------
__global__ __launch_bounds__(TPB) void k_pull(const float* __restrict__ feat,
                                              const int* __restrict__ gt,
                                              const float* __restrict__ ws,
                                              float* __restrict__ out) {
    __shared__ float s_cen[C_][N_ + 1];
    __shared__ float s_w[C_];
    __shared__ float s_cntv[B_ * C_];
    __shared__ float red[TPB];
    __shared__ float wsum[TPB / 64];

    const int tid   = threadIdx.x;
    const int b     = blockIdx.x / PBPI;
    const int chunk = blockIdx.x % PBPI;
    const int base  = chunk * PCHUNK;

    const float* __restrict__ fbase = feat + (size_t)b * N_ * P_ + base + tid * 4;

    // ---- issue first 8 channel loads + labels (fly during preamble) ----
    const int4 lb = *(const int4*)(gt + (size_t)b * P_ + base + tid * 4);
    float4 va[4], vb[4];
    #pragma unroll
    for (int j = 0; j < 4; ++j) va[j] = *(const float4*)(fbase + (size_t)(j) * P_);
    #pragma unroll
    for (int j = 0; j < 4; ++j) vb[j] = *(const float4*)(fbase + (size_t)(4 + j) * P_);

    // ---- preamble: counts -> n_inst, centers, weights ----
    if (tid < B_ * C_) s_cntv[tid] = ws[OFF_CNT + tid];
    __syncthreads();

    float n_inst = 0.f;
    #pragma unroll 8
    for (int i = 0; i < B_ * C_; ++i) n_inst += (s_cntv[i] > 0.f) ? 1.f : 0.f;

    if (tid < C_ * N_) {
        const int c = tid >> 4, n = tid & 15;
        const float ct = s_cntv[b * C_ + c];
        s_cen[c][n] = ws[OFF_SUMS + ((size_t)b * C_ + c) * N_ + n] / fmaxf(ct, 1.f);
    }
    if (tid < C_) {
        const float ct = s_cntv[b * C_ + tid];
        s_w[tid] = (ct > 0.f && n_inst > 0.f) ? 1.0f / (ct * n_inst) : 0.f;
    }
    __syncthreads();

    // ---- push loss: only the chunk==0 block of each image ----
    if (chunk == 0) {
        float ps = 0.f;
        if (tid < C_ * C_) {
            const int i = tid / C_, j = tid % C_;
            if (i != j && s_cntv[b * C_ + i] > 0.f && s_cntv[b * C_ + j] > 0.f) {
                float sq = 0.f;
                #pragma unroll
                for (int n = 0; n < N_; ++n) {
                    const float d = s_cen[i][n] - s_cen[j][n];
                    sq += d * d;
                }
                ps = fmaxf(2.f * MARGIN_DIST_ - sqrtf(sq), 0.f);
            }
        }
        red[tid] = ps;
        __syncthreads();
        for (int s = TPB / 2; s > 0; s >>= 1) {
            if (tid < s) red[tid] += red[tid + s];
            __syncthreads();
        }
        if (tid == 0) {
            float np = 0.f;
            for (int bb_ = 0; bb_ < B_; ++bb_) {
                int k = 0;
                for (int c = 0; c < C_; ++c) k += (s_cntv[bb_ * C_ + c] > 0.f) ? 1 : 0;
                np += (float)(k * (k - 1));
            }
            if (np > 0.f) atomicAdd(out, red[0] / np);   // DIST_WEIGHT = 1
        }
    }

    // ---- pull main: 4 pixels/thread, channel groups pipelined ----
    const bool vx = (lb.x >= 1 && lb.x <= C_);
    const bool vy = (lb.y >= 1 && lb.y <= C_);
    const bool vz = (lb.z >= 1 && lb.z <= C_);
    const bool vw = (lb.w >= 1 && lb.w <= C_);
    const int cx = vx ? lb.x - 1 : 0;
    const int cy = vy ? lb.y - 1 : 0;
    const int cz = vz ? lb.z - 1 : 0;
    const int cw = vw ? lb.w - 1 : 0;

    float sq0 = 0.f, sq1 = 0.f, sq2 = 0.f, sq3 = 0.f;

    auto consume4 = [&](const float4* r, int cb) {
        #pragma unroll
        for (int j = 0; j < 4; ++j) {
            const int nn = cb + j;
            const float d0 = r[j].x - s_cen[cx][nn];
            const float d1 = r[j].y - s_cen[cy][nn];
            const float d2 = r[j].z - s_cen[cz][nn];
            const float d3 = r[j].w - s_cen[cw][nn];
            sq0 += d0 * d0; sq1 += d1 * d1; sq2 += d2 * d2; sq3 += d3 * d3;
        }
    };

    consume4(va, 0);
    #pragma unroll
    for (int j = 0; j < 4; ++j) va[j] = *(const float4*)(fbase + (size_t)(8 + j) * P_);
    consume4(vb, 4);
    #pragma unroll
    for (int j = 0; j < 4; ++j) vb[j] = *(const float4*)(fbase + (size_t)(12 + j) * P_);
    consume4(va, 8);
    consume4(vb, 12);

    float acc = 0.f;
    acc += fmaxf(sqrtf(sq0) - MARGIN_VAR_, 0.f) * (vx ? s_w[cx] : 0.f);
    acc += fmaxf(sqrtf(sq1) - MARGIN_VAR_, 0.f) * (vy ? s_w[cy] : 0.f);
    acc += fmaxf(sqrtf(sq2) - MARGIN_VAR_, 0.f) * (vz ? s_w[cz] : 0.f);
    acc += fmaxf(sqrtf(sq3) - MARGIN_VAR_, 0.f) * (vw ? s_w[cw] : 0.f);

    #pragma unroll
    for (int off = 32; off > 0; off >>= 1) acc += __shfl_down(acc, off, 64);
    const int lane = tid & 63, wid = tid >> 6;
    if (lane == 0) wsum[wid] = acc;
    __syncthreads();
    if (tid == 0) {
        float t = 0.f;
        #pragma unroll
        for (int w = 0; w < TPB / 64; ++w) t += wsum[w];
        atomicAdd(out, t);   // VAR_WEIGHT = 1
    }
}

// ---------------------------------------------------------------------------
extern "C" void kernel_launch(void* const* d_in, const int* in_sizes, int n_in,
                              void* d_out, int out_size, void* d_ws, size_t ws_size,
                              hipStream_t stream) {
    const float* feat = (const float*)d_in[0];
    const int*   gt   = (const int*)d_in[1];
    float* out = (float*)d_out;
    float* ws  = (float*)d_ws;

    (void)hipMemsetAsync(d_ws, 0, WS_FLOATS * sizeof(float), stream);

    k_accum<<<dim3(B_ * MBPI), dim3(TPB), 0, stream>>>(feat, gt, ws, out);
    k_pull <<<dim3(B_ * PBPI), dim3(TPB), 0, stream>>>(feat, gt, ws, out);
}

// Round 9
// 68.824 us; speedup vs baseline: 4.0167x; 1.0242x over previous
//
#include <hip/hip_runtime.h>
#include <hip/hip_bf16.h>

// Problem constants (fixed by reference setup_inputs)
constexpr int B_ = 8;
constexpr int N_ = 16;
constexpr int H_ = 368;
constexpr int W_ = 640;
constexpr int P_ = H_ * W_;          // 235520 pixels per image
constexpr int C_ = 12;               // instance ids 1..12
constexpr float MARGIN_VAR_ = 0.5f;
constexpr float MARGIN_DIST_ = 3.0f;

// Workspace layout (floats): sums + counts
constexpr int OFF_SUMS = 0;                      // [B][C][N] feature sums
constexpr int OFF_CNT  = OFF_SUMS + B_*C_*N_;    // [B][C]    pixel counts
constexpr int WS_FLOATS = OFF_CNT + B_*C_;       // 1632 floats

constexpr int TPB = 256;

constexpr int MCHUNK = 1024;           // k_accum pixels per block
constexpr int MBPI   = P_ / MCHUNK;    // 230 (exact)
constexpr int PCHUNK = 1024;           // k_pull pixels per block
constexpr int PBPI   = P_ / PCHUNK;    // 230 (exact)
constexpr int NBLK   = B_ * PBPI;      // 1840

// bf16 LDS tile: 16 rows x 1024 px, row stride padded +24 shorts (48 B)
// -> bank shift 12/row -> 16 rows alias 2-way (free, m136).
constexpr int ROWS_ = 1048;            // shorts per row (1024 + 24 pad)

typedef short bf16x8 __attribute__((ext_vector_type(8)));   // 8 bf16 (4 VGPR)
typedef float f32x4  __attribute__((ext_vector_type(4)));   // MFMA accumulator

union FragU { int4 i; bf16x8 v; };

__device__ __forceinline__ short f2bf(float f) {
    __hip_bfloat16 h = __float2bfloat16(f);
    return __builtin_bit_cast(short, h);
}

__device__ __forceinline__ int pack_bf2(float x, float y) {
    const unsigned lo = (unsigned short)f2bf(x);
    const unsigned hi = (unsigned short)f2bf(y);
    return (int)(lo | (hi << 16));
}

// ---------------------------------------------------------------------------
// Kernel 1: per-class feature sums + counts via MFMA, LDS-staged.
// Stage: 16 coalesced float4 loads/thread (1 KB/inst) -> bf16 -> LDS tile.
// MFMA: A = class masks from labels, B = bf16 feat from LDS (ds_read_b128).
// ---------------------------------------------------------------------------
__global__ __launch_bounds__(TPB) void k_accum(const float* __restrict__ feat,
                                               const int* __restrict__ gt,
                                               float* __restrict__ ws,
                                               float* __restrict__ out) {
    __shared__ int   s_lab[MCHUNK];          // 4 KB
    __shared__ short s_feat[N_ * ROWS_];     // 33.5 KB bf16 tile
    __shared__ float s_red[4][C_];
    __shared__ float s_fin[4][256];          // 4 KB: per-wave D elements

    const int tid  = threadIdx.x;
    const int lane = tid & 63, wid = tid >> 6;
    const int b     = blockIdx.x / MBPI;
    const int chunk = blockIdx.x % MBPI;
    const int base  = chunk * MCHUNK;

    if (blockIdx.x == 0 && tid == 0) out[0] = 0.f;   // init output before k_pull

    const int*   __restrict__ gb = gt   + (size_t)b * P_ + base;
    const float* __restrict__ fb = feat + (size_t)b * N_ * P_ + base;

    // ---- stage labels (1 int4/thread) ----
    const int4 la = ((const int4*)gb)[tid];
    ((int4*)s_lab)[tid] = la;

    // ---- stage feat -> bf16 LDS, 8+8 pipelined coalesced loads ----
    float4 g[8];
    #pragma unroll
    for (int j = 0; j < 8; ++j)
        g[j] = *(const float4*)(fb + (size_t)j * P_ + tid * 4);
    #pragma unroll
    for (int j = 0; j < 8; ++j) {
        const float4 v = g[j];
        g[j] = *(const float4*)(fb + (size_t)(8 + j) * P_ + tid * 4);
        int2 w; w.x = pack_bf2(v.x, v.y); w.y = pack_bf2(v.z, v.w);
        *(int2*)(s_feat + j * ROWS_ + tid * 4) = w;
    }
    #pragma unroll
    for (int j = 0; j < 8; ++j) {
        const float4 v = g[j];
        int2 w; w.x = pack_bf2(v.x, v.y); w.y = pack_bf2(v.z, v.w);
        *(int2*)(s_feat + (8 + j) * ROWS_ + tid * 4) = w;
    }

    // ---- per-class counts (overlaps with staging stores) ----
    float cnt[C_];
    #pragma unroll
    for (int c = 0; c < C_; ++c) {
        cnt[c] = ((la.x == c+1) ? 1.f : 0.f) + ((la.y == c+1) ? 1.f : 0.f)
               + ((la.z == c+1) ? 1.f : 0.f) + ((la.w == c+1) ? 1.f : 0.f);
    }
    #pragma unroll
    for (int off = 32; off > 0; off >>= 1) {
        #pragma unroll
        for (int c = 0; c < C_; ++c) cnt[c] += __shfl_xor(cnt[c], off, 64);
    }
    if (lane == 0) {
        #pragma unroll
        for (int c = 0; c < C_; ++c) s_red[wid][c] = cnt[c];
    }
    __syncthreads();   // labels + feat tile + s_red ready
    if (tid < C_) {
        const float t = s_red[0][tid] + s_red[1][tid] + s_red[2][tid] + s_red[3][tid];
        atomicAdd(&ws[OFF_CNT + b * C_ + tid], t);
    }

    // ---- MFMA main: wave w handles k-chunks t = w*8 .. w*8+7 ----
    const int n   = lane & 15;              // class-1 (A row) / channel (B col)
    const int cls = n + 1;
    const int ko  = (lane >> 4) * 8;        // k-octet within 32-px chunk

    const short* __restrict__ bp = s_feat + n * ROWS_ + ko;   // lane's B base

    f32x4 acc = {0.f, 0.f, 0.f, 0.f};

    #pragma unroll
    for (int k = 0; k < 8; ++k) {
        const int t = wid * 8 + k;
        const int* lp = s_lab + t * 32 + ko;
        const int4 L0 = *(const int4*)(lp);
        const int4 L1 = *(const int4*)(lp + 4);

        FragU au, bu;
        au.i.x = ((L0.x == cls) ? 0x3F80 : 0) | ((L0.y == cls) ? 0x3F800000 : 0);
        au.i.y = ((L0.z == cls) ? 0x3F80 : 0) | ((L0.w == cls) ? 0x3F800000 : 0);
        au.i.z = ((L1.x == cls) ? 0x3F80 : 0) | ((L1.y == cls) ? 0x3F800000 : 0);
        au.i.w = ((L1.z == cls) ? 0x3F80 : 0) | ((L1.w == cls) ? 0x3F800000 : 0);

        bu.v = *(const bf16x8*)(bp + t * 32);   // 16 B aligned ds_read_b128

        acc = __builtin_amdgcn_mfma_f32_16x16x32_bf16(au.v, bu.v, acc, 0, 0, 0);
    }

    // ---- cross-wave reduce of D, then one atomic per (class,channel) ----
    #pragma unroll
    for (int r = 0; r < 4; ++r) s_fin[wid][lane * 4 + r] = acc[r];
    __syncthreads();

    {   // element e = tid: lane = e>>2, reg = e&3
        const float sv = s_fin[0][tid] + s_fin[1][tid] + s_fin[2][tid] + s_fin[3][tid];
        const int elane = tid >> 2, r = tid & 3;
        const int row = (elane >> 4) * 4 + r;   // class (D row)
        const int col = elane & 15;             // channel (D col)
        if (row < C_)
            atomicAdd(&ws[OFF_SUMS + ((size_t)b * C_ + row) * N_ + col], sv);
    }
}

// ---------------------------------------------------------------------------
// Kernel 2: pull loss + push loss. Chunk mapping reversed within each XCD
// congruence class so early blocks hit L2 lines k_accum touched last.
// ---------------------------------------------------------------------------
__global__ __launch_bounds__(TPB) void k_pull(const float* __restrict__ feat,
                                              const int* __restrict__ gt,
                                              const float* __restrict__ ws,
                                              float* __restrict__ out) {
    __shared__ float s_cen[C_][N_ + 1];
    __shared__ float s_w[C_];
    __shared__ float s_cntv[B_ * C_];
    __shared__ float red[TPB];
    __shared__ float wsum[TPB / 64];

    const int tid = threadIdx.x;
    // reverse round order, keep blockIdx%8 (same-XCD) alignment
    const int g2    = (NBLK / 8 - 1 - (int)(blockIdx.x >> 3)) * 8 + (blockIdx.x & 7);
    const int b     = g2 / PBPI;
    const int chunk = g2 % PBPI;
    const int base  = chunk * PCHUNK;

    const float* __restrict__ fbase = feat + (size_t)b * N_ * P_ + base + tid * 4;

    // ---- issue first 8 channel loads + labels (fly during preamble) ----
    const int4 lb = *(const int4*)(gt + (size_t)b * P_ + base + tid * 4);
    float4 va[4], vb[4];
    #pragma unroll
    for (int j = 0; j < 4; ++j) va[j] = *(const float4*)(fbase + (size_t)(j) * P_);
    #pragma unroll
    for (int j = 0; j < 4; ++j) vb[j] = *(const float4*)(fbase + (size_t)(4 + j) * P_);

    // ---- preamble: counts -> n_inst, centers, weights ----
    if (tid < B_ * C_) s_cntv[tid] = ws[OFF_CNT + tid];
    __syncthreads();

    float n_inst = 0.f;
    #pragma unroll 8
    for (int i = 0; i < B_ * C_; ++i) n_inst += (s_cntv[i] > 0.f) ? 1.f : 0.f;

    if (tid < C_ * N_) {
        const int c = tid >> 4, n = tid & 15;
        const float ct = s_cntv[b * C_ + c];
        s_cen[c][n] = ws[OFF_SUMS + ((size_t)b * C_ + c) * N_ + n] / fmaxf(ct, 1.f);
    }
    if (tid < C_) {
        const float ct = s_cntv[b * C_ + tid];
        s_w[tid] = (ct > 0.f && n_inst > 0.f) ? 1.0f / (ct * n_inst) : 0.f;
    }
    __syncthreads();

    // ---- push loss: only the chunk==0 block of each image ----
    if (chunk == 0) {
        float ps = 0.f;
        if (tid < C_ * C_) {
            const int i = tid / C_, j = tid % C_;
            if (i != j && s_cntv[b * C_ + i] > 0.f && s_cntv[b * C_ + j] > 0.f) {
                float sq = 0.f;
                #pragma unroll
                for (int n = 0; n < N_; ++n) {
                    const float d = s_cen[i][n] - s_cen[j][n];
                    sq += d * d;
                }
                ps = fmaxf(2.f * MARGIN_DIST_ - sqrtf(sq), 0.f);
            }
        }
        red[tid] = ps;
        __syncthreads();
        for (int s = TPB / 2; s > 0; s >>= 1) {
            if (tid < s) red[tid] += red[tid + s];
            __syncthreads();
        }
        if (tid == 0) {
            float np = 0.f;
            for (int bb_ = 0; bb_ < B_; ++bb_) {
                int k = 0;
                for (int c = 0; c < C_; ++c) k += (s_cntv[bb_ * C_ + c] > 0.f) ? 1 : 0;
                np += (float)(k * (k - 1));
            }
            if (np > 0.f) atomicAdd(out, red[0] / np);   // DIST_WEIGHT = 1
        }
    }

    // ---- pull main: 4 pixels/thread, channel groups pipelined ----
    const bool vx = (lb.x >= 1 && lb.x <= C_);
    const bool vy = (lb.y >= 1 && lb.y <= C_);
    const bool vz = (lb.z >= 1 && lb.z <= C_);
    const bool vw = (lb.w >= 1 && lb.w <= C_);
    const int cx = vx ? lb.x - 1 : 0;
    const int cy = vy ? lb.y - 1 : 0;
    const int cz = vz ? lb.z - 1 : 0;
    const int cw = vw ? lb.w - 1 : 0;

    float sq0 = 0.f, sq1 = 0.f, sq2 = 0.f, sq3 = 0.f;

    auto consume4 = [&](const float4* r, int cb) {
        #pragma unroll
        for (int j = 0; j < 4; ++j) {
            const int nn = cb + j;
            const float d0 = r[j].x - s_cen[cx][nn];
            const float d1 = r[j].y - s_cen[cy][nn];
            const float d2 = r[j].z - s_cen[cz][nn];
            const float d3 = r[j].w - s_cen[cw][nn];
            sq0 += d0 * d0; sq1 += d1 * d1; sq2 += d2 * d2; sq3 += d3 * d3;
        }
    };

    consume4(va, 0);
    #pragma unroll
    for (int j = 0; j < 4; ++j) va[j] = *(const float4*)(fbase + (size_t)(8 + j) * P_);
    consume4(vb, 4);
    #pragma unroll
    for (int j = 0; j < 4; ++j) vb[j] = *(const float4*)(fbase + (size_t)(12 + j) * P_);
    consume4(va, 8);
    consume4(vb, 12);

    float acc = 0.f;
    acc += fmaxf(sqrtf(sq0) - MARGIN_VAR_, 0.f) * (vx ? s_w[cx] : 0.f);
    acc += fmaxf(sqrtf(sq1) - MARGIN_VAR_, 0.f) * (vy ? s_w[cy] : 0.f);
    acc += fmaxf(sqrtf(sq2) - MARGIN_VAR_, 0.f) * (vz ? s_w[cz] : 0.f);
    acc += fmaxf(sqrtf(sq3) - MARGIN_VAR_, 0.f) * (vw ? s_w[cw] : 0.f);

    #pragma unroll
    for (int off = 32; off > 0; off >>= 1) acc += __shfl_down(acc, off, 64);
    const int lane = tid & 63, wid = tid >> 6;
    if (lane == 0) wsum[wid] = acc;
    __syncthreads();
    if (tid == 0) {
        float t = 0.f;
        #pragma unroll
        for (int w = 0; w < TPB / 64; ++w) t += wsum[w];
        atomicAdd(out, t);   // VAR_WEIGHT = 1
    }
}

// ---------------------------------------------------------------------------
extern "C" void kernel_launch(void* const* d_in, const int* in_sizes, int n_in,
                              void* d_out, int out_size, void* d_ws, size_t ws_size,
                              hipStream_t stream) {
    const float* feat = (const float*)d_in[0];
    const int*   gt   = (const int*)d_in[1];
    float* out = (float*)d_out;
    float* ws  = (float*)d_ws;

    (void)hipMemsetAsync(d_ws, 0, WS_FLOATS * sizeof(float), stream);

    k_accum<<<dim3(B_ * MBPI), dim3(TPB), 0, stream>>>(feat, gt, ws, out);
    k_pull <<<dim3(NBLK), dim3(TPB), 0, stream>>>(feat, gt, ws, out);
}